// Round 7
// baseline (264.956 us; speedup 1.0000x reference)
//
#include <hip/hip_runtime.h>
#include <stdint.h>

typedef __bf16 bf16x8 __attribute__((ext_vector_type(8)));
typedef float  f32x4  __attribute__((ext_vector_type(4)));
typedef unsigned short u16x8 __attribute__((ext_vector_type(8)));

typedef __attribute__((address_space(3))) void lds_void;
typedef __attribute__((address_space(1))) const void gbl_cvoid;

__device__ __forceinline__ unsigned short f2bf(float f) {
  union { float f; uint32_t u; } v; v.f = f;
  return (unsigned short)((v.u + 0x7FFFu + ((v.u >> 16) & 1u)) >> 16);
}

// ---------------- prep: fused cvt(x,w1,w2) + butterfly weight gather ---------
__global__ void prep_kernel(const float* __restrict__ x,
                            const float* __restrict__ weight,
                            const float* __restrict__ w1,
                            const float* __restrict__ w2,
                            const int* __restrict__ flat,
                            unsigned short* __restrict__ xb,
                            unsigned short* __restrict__ w1b,
                            unsigned short* __restrict__ w2b,
                            unsigned short* __restrict__ weff) {
  const int NX = (4096 * 4096) / 8;   // 2097152
  const int NW = (256 * 4096) / 8;    // 131072
  const int NF = (20480 * 256) / 8;   // 655360
  const int total = NX + 2 * NW + NF;
  for (int i = blockIdx.x * 256 + threadIdx.x; i < total; i += gridDim.x * 256) {
    const float* src;
    unsigned short* dst;
    if (i < NX) {
      src = x + (size_t)i * 8;  dst = xb + (size_t)i * 8;
    } else if (i < NX + NW) {
      int k = i - NX;
      src = w1 + (size_t)k * 8; dst = w1b + (size_t)k * 8;
    } else if (i < NX + 2 * NW) {
      int k = i - NX - NW;
      src = w2 + (size_t)k * 8; dst = w2b + (size_t)k * 8;
    } else {
      int widx = i - NX - 2 * NW;           // 0..655359
      int row = widx >> 5;                  // 0..20479
      int c8 = (widx & 31) << 3;
      int ob = row / 1280;
      int t  = row - ob * 1280;
      int s  = t >> 8;
      int r  = t & 255;
      int f  = flat[ob * 5 + s];
      int q  = f / 5;
      int jj = f - q * 5;
      int k  = (jj << 8) + r;
      int i2 = k / 5;
      int a  = k - i2 * 5;
      src = weight + ((size_t)((q << 8) + i2) * 5 + a) * 256 + c8;
      dst = weff + (size_t)row * 256 + c8;
    }
    f32x4 va = ((const f32x4*)src)[0], vb = ((const f32x4*)src)[1];
    u16x8 o;
    o[0] = f2bf(va[0]); o[1] = f2bf(va[1]); o[2] = f2bf(va[2]); o[3] = f2bf(va[3]);
    o[4] = f2bf(vb[0]); o[5] = f2bf(vb[1]); o[6] = f2bf(vb[2]); o[7] = f2bf(vb[3]);
    *(u16x8*)dst = o;
  }
}

// ---------------- t1 = x @ w1^T, intra-block split-K x2, bf16 out ------------
// 256 blocks (64x64 tile), 8 waves: waves 0-3 K[0:2048), waves 4-7 K[2048:4096).
// Each half: independent 2-deep counted-vmcnt pipeline in its own 32KB LDS.
__global__ __launch_bounds__(512) void t1_gemm_kernel(
    const unsigned short* __restrict__ xb,
    const unsigned short* __restrict__ w1b,
    unsigned short* __restrict__ t1out) {
  __shared__ __align__(16) char smem[65536];  // 2 halves x dbuf x (A 8K + B 8K)
  const int tid = threadIdx.x, lane = tid & 63, w = tid >> 6;
  const int half = w >> 2, hw = w & 3;
  const int wr = hw >> 1, wc = hw & 1;
  const int lr = lane & 15, lk = lane >> 4, lr7 = lr & 7;
  const int row0 = blockIdx.x << 6, col0 = blockIdx.y << 6;
  const int htid = tid & 255;
  const int rr = htid >> 3;                   // 0..31
  const int csw = (htid & 7) ^ (rr & 7);
  const int cs0 = (lk ^ lr7) << 4, cs1 = ((4 | lk) ^ lr7) << 4;
  const int aRow = ((wr << 5) + lr) << 7;
  const int bRow = ((wc << 5) + lr) << 7;
  char* hbase = smem + (half << 15);

  const unsigned short* As = xb  + (size_t)(row0 + rr) * 4096 + (half << 11) + csw * 8;
  const unsigned short* Bs = w1b + (size_t)(col0 + rr) * 4096 + (half << 11) + csw * 8;

  f32x4 acc[2][2];
#pragma unroll
  for (int m = 0; m < 2; ++m)
#pragma unroll
    for (int n = 0; n < 2; ++n) acc[m][n] = (f32x4){0.f, 0.f, 0.f, 0.f};

  auto STAGE = [&](int t) {
    char* d = hbase + ((t & 1) << 14) + (htid << 4);
    const unsigned short* a = As + (t << 6);
    const unsigned short* bp = Bs + (t << 6);
    __builtin_amdgcn_global_load_lds((gbl_cvoid*)a, (lds_void*)d, 16, 0, 0);
    __builtin_amdgcn_global_load_lds((gbl_cvoid*)(a + (size_t)32 * 4096), (lds_void*)(d + 4096), 16, 0, 0);
    __builtin_amdgcn_global_load_lds((gbl_cvoid*)bp, (lds_void*)(d + 8192), 16, 0, 0);
    __builtin_amdgcn_global_load_lds((gbl_cvoid*)(bp + (size_t)32 * 4096), (lds_void*)(d + 12288), 16, 0, 0);
  };

  STAGE(0);
#pragma unroll 1
  for (int t = 0; t < 32; ++t) {
    if (t < 31) {
      STAGE(t + 1);
      asm volatile("s_waitcnt vmcnt(4)" ::: "memory");   // stage(t) landed
    } else {
      asm volatile("s_waitcnt vmcnt(0)" ::: "memory");
    }
    __builtin_amdgcn_s_barrier();
    const char* Ab = hbase + ((t & 1) << 14);
    const char* Bb = Ab + 8192;
    bf16x8 aq[2][2], bq[2][2];
#pragma unroll
    for (int m = 0; m < 2; ++m) {
      aq[m][0] = *(const bf16x8*)(Ab + aRow + m * 2048 + cs0);
      aq[m][1] = *(const bf16x8*)(Ab + aRow + m * 2048 + cs1);
      bq[m][0] = *(const bf16x8*)(Bb + bRow + m * 2048 + cs0);
      bq[m][1] = *(const bf16x8*)(Bb + bRow + m * 2048 + cs1);
    }
#pragma unroll
    for (int m = 0; m < 2; ++m)
#pragma unroll
      for (int n = 0; n < 2; ++n) {
        acc[m][n] = __builtin_amdgcn_mfma_f32_16x16x32_bf16(aq[m][0], bq[n][0], acc[m][n], 0, 0, 0);
        acc[m][n] = __builtin_amdgcn_mfma_f32_16x16x32_bf16(aq[m][1], bq[n][1], acc[m][n], 0, 0, 0);
      }
    asm volatile("" ::: "memory");
    __builtin_amdgcn_s_barrier();
  }

  // combine the two K-halves via LDS, write bf16
  __syncthreads();
  if (half == 1) {
#pragma unroll
    for (int m = 0; m < 2; ++m)
#pragma unroll
      for (int n = 0; n < 2; ++n)
        *(f32x4*)(smem + ((((hw << 2) + (m << 1) + n) << 6) + lane) * 16) = acc[m][n];
  }
  __syncthreads();
  if (half == 0) {
#pragma unroll
    for (int m = 0; m < 2; ++m)
#pragma unroll
      for (int n = 0; n < 2; ++n) {
        f32x4 p = *(const f32x4*)(smem + ((((hw << 2) + (m << 1) + n) << 6) + lane) * 16);
        int row = row0 + (wr << 5) + (m << 4) + (lk << 2);
        int col = col0 + (wc << 5) + (n << 4) + lr;
#pragma unroll
        for (int jj = 0; jj < 4; ++jj)
          t1out[(size_t)(row + jj) * 256 + col] = f2bf(acc[m][n][jj] + p[jj]);
      }
  }
}

// ---------------- main: 256x256, 8-phase quadrant schedule, counted vmcnt ----
// 24 K-tiles (BK=64) over 6 panels; dbuf (tile&1); per phase the BLOCK computes
// one 128x128 C-quadrant (reads one A-half + one B-half) and stages exactly one
// half-tile whose old data's last reader was a previous phase. vmcnt(4) at
// phases 4 and 8 only.
__global__ __launch_bounds__(512, 2) void main_gemm_kernel(
    const unsigned short* __restrict__ xb,
    const unsigned short* __restrict__ t1,
    const unsigned short* __restrict__ w2b,
    const unsigned short* __restrict__ weff,
    const int* __restrict__ flat,
    const float* __restrict__ bias,
    float* __restrict__ out) {
  __shared__ __align__(16) char smem[131072];  // 2 bufs x {A 32K | B 32K}
  const int tid  = threadIdx.x;
  const int lane = tid & 63;
  const int w    = tid >> 6;                   // 0..7
  const int wq   = w >> 1;                     // 0..3: 32-row strip in quadrant
  const int wc1  = w & 1;                      // 0..1: 64-col half in quadrant
  const int lr   = lane & 15, lk = lane >> 4, lr7 = lr & 7;

  int bid = blockIdx.x;
  int swz = ((bid & 7) << 5) | (bid >> 3);     // bijective: 256 % 8 == 0
  const int bx = swz >> 4, by = swz & 15;
  const int row0 = bx << 8, col0 = by << 8;    // BM = BN = 256; ob == by

  const int rr0 = tid >> 3;                    // 0..63
  const int csw = (tid & 7) ^ (rr0 & 7);

  const int base5 = by * 5;
  const int cA1 = (flat[base5 + 0] / 5) << 8;
  const int cA2 = (flat[base5 + 1] / 5) << 8;
  const int cA3 = (flat[base5 + 2] / 5) << 8;
  const int cA4 = (flat[base5 + 3] / 5) << 8;
  const int cA5 = (flat[base5 + 4] / 5) << 8;

  f32x4 acc[4][8];
#pragma unroll
  for (int m = 0; m < 4; ++m)
#pragma unroll
    for (int n = 0; n < 8; ++n) acc[m][n] = (f32x4){0.f, 0.f, 0.f, 0.f};

  // stage half-tile idx of K-tile T. idx: 0=A rows0-127, 1=A rows128-255,
  // 2=B rows0-127, 3=B rows128-255. Each = 2 global_load_lds (8KB each).
  auto stage = [&](int T, int idx) {
    if (T >= 24) return;
    int s = T >> 2, k0 = (T & 3) << 6;
    char* dst = smem + ((T & 1) << 16) + (idx << 14) + (tid << 4);
    int rbase = ((idx & 1) << 7) + rr0;
    if (idx < 2) {
      const unsigned short* Ab;
      int Astr;
      if (s == 0) { Ab = t1 + (size_t)row0 * 256; Astr = 256; }
      else {
        int colA = (s == 1) ? cA1 : (s == 2) ? cA2 : (s == 3) ? cA3
                 : (s == 4) ? cA4 : cA5;
        Ab = xb + (size_t)row0 * 4096 + colA; Astr = 4096;
      }
      const unsigned short* src = Ab + (size_t)rbase * Astr + k0 + csw * 8;
      __builtin_amdgcn_global_load_lds((gbl_cvoid*)src, (lds_void*)dst, 16, 0, 0);
      __builtin_amdgcn_global_load_lds((gbl_cvoid*)(src + (size_t)64 * Astr),
                                       (lds_void*)(dst + 8192), 16, 0, 0);
    } else {
      const unsigned short* Bb = (s == 0)
          ? (w2b + (size_t)col0 * 256)
          : (weff + ((size_t)(base5 + s - 1) << 16));
      const unsigned short* src = Bb + (size_t)rbase * 256 + k0 + csw * 8;
      __builtin_amdgcn_global_load_lds((gbl_cvoid*)src, (lds_void*)dst, 16, 0, 0);
      __builtin_amdgcn_global_load_lds((gbl_cvoid*)(src + 64 * 256),
                                       (lds_void*)(dst + 8192), 16, 0, 0);
    }
  };

  // one phase: block computes quadrant (mq,nq) of tile in `buf`; stages one
  // half-tile; vm: -1 none, 4 counted, 0 drain.
  auto phase = [&](const char* buf, int mq, int nq, int stT, int stIdx, int vm) {
    bf16x8 aq[2][2], bq[4][2];
    const int abase = mq * 128 + wq * 32;
    const int bbase = nq * 128 + wc1 * 64;
#pragma unroll
    for (int m = 0; m < 2; ++m) {
      int row = abase + m * 16 + lr;
#pragma unroll
      for (int kk = 0; kk < 2; ++kk)
        aq[m][kk] = *(const bf16x8*)(buf + row * 128 + (((kk << 2) | lk) ^ lr7) * 16);
    }
#pragma unroll
    for (int n = 0; n < 4; ++n) {
      int row = bbase + n * 16 + lr;
#pragma unroll
      for (int kk = 0; kk < 2; ++kk)
        bq[n][kk] = *(const bf16x8*)(buf + 32768 + row * 128 + (((kk << 2) | lk) ^ lr7) * 16);
    }
    stage(stT, stIdx);
    asm volatile("" ::: "memory");
    __builtin_amdgcn_s_barrier();
    __builtin_amdgcn_s_setprio(1);
#pragma unroll
    for (int m = 0; m < 2; ++m)
#pragma unroll
      for (int n = 0; n < 4; ++n) {
        acc[(mq << 1) | m][(nq << 2) | n] = __builtin_amdgcn_mfma_f32_16x16x32_bf16(
            aq[m][0], bq[n][0], acc[(mq << 1) | m][(nq << 2) | n], 0, 0, 0);
        acc[(mq << 1) | m][(nq << 2) | n] = __builtin_amdgcn_mfma_f32_16x16x32_bf16(
            aq[m][1], bq[n][1], acc[(mq << 1) | m][(nq << 2) | n], 0, 0, 0);
      }
    __builtin_amdgcn_s_setprio(0);
    if (vm == 4)      asm volatile("s_waitcnt vmcnt(4)" ::: "memory");
    else if (vm == 0) asm volatile("s_waitcnt vmcnt(0)" ::: "memory");
    asm volatile("" ::: "memory");
    __builtin_amdgcn_s_barrier();
  };

  // prologue: tile0 fully + tile1 A0,B0; vmcnt(4) => tile0 landed
  stage(0, 0); stage(0, 1); stage(0, 2); stage(0, 3);
  stage(1, 0); stage(1, 2);
  asm volatile("s_waitcnt vmcnt(4)" ::: "memory");
  __builtin_amdgcn_s_barrier();

  const char* b0 = smem;
  const char* b1 = smem + 65536;
#pragma unroll 1
  for (int i = 0; i < 12; ++i) {
    int Ta = 2 * i, Tb = Ta + 1;
    int last = (i == 11);
    phase(b0, 0, 0, Tb, 1, -1);
    phase(b0, 0, 1, Tb, 3, -1);
    phase(b0, 1, 0, Ta + 2, 0, -1);
    phase(b0, 1, 1, Ta + 2, 2, last ? 0 : 4);
    phase(b1, 0, 0, Ta + 2, 1, -1);
    phase(b1, 0, 1, Ta + 2, 3, -1);
    phase(b1, 1, 0, Ta + 3, 0, -1);
    phase(b1, 1, 1, Ta + 3, 2, last ? -1 : 4);
  }

  // epilogue: + bias, f32 store
#pragma unroll
  for (int N = 0; N < 8; ++N) {
    int col = col0 + ((N >> 2) << 7) + (wc1 << 6) + ((N & 3) << 4) + lr;
    float bv = bias[col];
#pragma unroll
    for (int M = 0; M < 4; ++M) {
      int row = row0 + ((M >> 1) << 7) + (wq << 5) + ((M & 1) << 4) + (lk << 2);
#pragma unroll
      for (int jj = 0; jj < 4; ++jj)
        out[(size_t)(row + jj) * 4096 + col] = acc[M][N][jj] + bv;
    }
  }
}

extern "C" void kernel_launch(void* const* d_in, const int* in_sizes, int n_in,
                              void* d_out, int out_size, void* d_ws, size_t ws_size,
                              hipStream_t stream) {
  const float* x      = (const float*)d_in[0];
  const float* weight = (const float*)d_in[1];
  const float* w1     = (const float*)d_in[2];
  const float* w2     = (const float*)d_in[3];
  const float* b      = (const float*)d_in[4];
  const int*   flat   = (const int*)d_in[5];
  float* out = (float*)d_out;

  char* ws = (char*)d_ws;
  unsigned short* xb   = (unsigned short*)(ws);                  // 32 MiB
  unsigned short* w1b  = (unsigned short*)(ws + 33554432);       // 2 MiB
  unsigned short* w2b  = (unsigned short*)(ws + 35651584);       // 2 MiB
  unsigned short* weff = (unsigned short*)(ws + 37748736);       // 10 MiB
  unsigned short* t1   = (unsigned short*)(ws + 48234496);       // 2 MiB

  prep_kernel<<<2048, 256, 0, stream>>>(x, weight, w1, w2, flat, xb, w1b, w2b, weff);
  t1_gemm_kernel<<<dim3(64, 4), 512, 0, stream>>>(xb, w1b, t1);
  main_gemm_kernel<<<256, 512, 0, stream>>>(xb, t1, w2b, weff, flat, b, out);
}

// Round 8
// 219.697 us; speedup vs baseline: 1.2060x; 1.2060x over previous
//
#include <hip/hip_runtime.h>
#include <stdint.h>

typedef __bf16 bf16x8 __attribute__((ext_vector_type(8)));
typedef float  f32x4  __attribute__((ext_vector_type(4)));
typedef unsigned short u16x8 __attribute__((ext_vector_type(8)));

typedef __attribute__((address_space(3))) void lds_void;
typedef __attribute__((address_space(1))) const void gbl_cvoid;

__device__ __forceinline__ unsigned short f2bf(float f) {
  union { float f; uint32_t u; } v; v.f = f;
  return (unsigned short)((v.u + 0x7FFFu + ((v.u >> 16) & 1u)) >> 16);
}

// ---------------- prep: fused cvt(x,w1,w2) + butterfly weight gather ---------
__global__ void prep_kernel(const float* __restrict__ x,
                            const float* __restrict__ weight,
                            const float* __restrict__ w1,
                            const float* __restrict__ w2,
                            const int* __restrict__ flat,
                            unsigned short* __restrict__ xb,
                            unsigned short* __restrict__ w1b,
                            unsigned short* __restrict__ w2b,
                            unsigned short* __restrict__ weff) {
  const int NX = (4096 * 4096) / 8;   // 2097152
  const int NW = (256 * 4096) / 8;    // 131072
  const int NF = (20480 * 256) / 8;   // 655360
  const int total = NX + 2 * NW + NF;
  for (int i = blockIdx.x * 256 + threadIdx.x; i < total; i += gridDim.x * 256) {
    const float* src;
    unsigned short* dst;
    if (i < NX) {
      src = x + (size_t)i * 8;  dst = xb + (size_t)i * 8;
    } else if (i < NX + NW) {
      int k = i - NX;
      src = w1 + (size_t)k * 8; dst = w1b + (size_t)k * 8;
    } else if (i < NX + 2 * NW) {
      int k = i - NX - NW;
      src = w2 + (size_t)k * 8; dst = w2b + (size_t)k * 8;
    } else {
      int widx = i - NX - 2 * NW;           // 0..655359
      int row = widx >> 5;                  // 0..20479
      int c8 = (widx & 31) << 3;
      int ob = row / 1280;
      int t  = row - ob * 1280;
      int s  = t >> 8;
      int r  = t & 255;
      int f  = flat[ob * 5 + s];
      int q  = f / 5;
      int jj = f - q * 5;
      int k  = (jj << 8) + r;
      int i2 = k / 5;
      int a  = k - i2 * 5;
      src = weight + ((size_t)((q << 8) + i2) * 5 + a) * 256 + c8;
      dst = weff + (size_t)row * 256 + c8;
    }
    f32x4 va = ((const f32x4*)src)[0], vb = ((const f32x4*)src)[1];
    u16x8 o;
    o[0] = f2bf(va[0]); o[1] = f2bf(va[1]); o[2] = f2bf(va[2]); o[3] = f2bf(va[3]);
    o[4] = f2bf(vb[0]); o[5] = f2bf(vb[1]); o[6] = f2bf(vb[2]); o[7] = f2bf(vb[3]);
    *(u16x8*)dst = o;
  }
}

// ---------------- t1 = x @ w1^T, intra-block split-K x2, bf16 out ------------
__global__ __launch_bounds__(512) void t1_gemm_kernel(
    const unsigned short* __restrict__ xb,
    const unsigned short* __restrict__ w1b,
    unsigned short* __restrict__ t1out) {
  __shared__ __align__(16) char smem[65536];  // 2 halves x dbuf x (A 8K + B 8K)
  const int tid = threadIdx.x, lane = tid & 63, w = tid >> 6;
  const int half = w >> 2, hw = w & 3;
  const int wr = hw >> 1, wc = hw & 1;
  const int lr = lane & 15, lk = lane >> 4, lr7 = lr & 7;
  const int row0 = blockIdx.x << 6, col0 = blockIdx.y << 6;
  const int htid = tid & 255;
  const int rr = htid >> 3;                   // 0..31
  const int csw = (htid & 7) ^ (rr & 7);
  const int cs0 = (lk ^ lr7) << 4, cs1 = ((4 | lk) ^ lr7) << 4;
  const int aRow = ((wr << 5) + lr) << 7;
  const int bRow = ((wc << 5) + lr) << 7;
  char* hbase = smem + (half << 15);

  const unsigned short* As = xb  + (size_t)(row0 + rr) * 4096 + (half << 11) + csw * 8;
  const unsigned short* Bs = w1b + (size_t)(col0 + rr) * 4096 + (half << 11) + csw * 8;

  f32x4 acc[2][2];
#pragma unroll
  for (int m = 0; m < 2; ++m)
#pragma unroll
    for (int n = 0; n < 2; ++n) acc[m][n] = (f32x4){0.f, 0.f, 0.f, 0.f};

  auto STAGE = [&](int t) {
    char* d = hbase + ((t & 1) << 14) + (htid << 4);
    const unsigned short* a = As + (t << 6);
    const unsigned short* bp = Bs + (t << 6);
    __builtin_amdgcn_global_load_lds((gbl_cvoid*)a, (lds_void*)d, 16, 0, 0);
    __builtin_amdgcn_global_load_lds((gbl_cvoid*)(a + (size_t)32 * 4096), (lds_void*)(d + 4096), 16, 0, 0);
    __builtin_amdgcn_global_load_lds((gbl_cvoid*)bp, (lds_void*)(d + 8192), 16, 0, 0);
    __builtin_amdgcn_global_load_lds((gbl_cvoid*)(bp + (size_t)32 * 4096), (lds_void*)(d + 12288), 16, 0, 0);
  };

  STAGE(0);
#pragma unroll 1
  for (int t = 0; t < 32; ++t) {
    if (t < 31) {
      STAGE(t + 1);
      asm volatile("s_waitcnt vmcnt(4)" ::: "memory");   // stage(t) landed
    } else {
      asm volatile("s_waitcnt vmcnt(0)" ::: "memory");
    }
    __builtin_amdgcn_s_barrier();
    const char* Ab = hbase + ((t & 1) << 14);
    const char* Bb = Ab + 8192;
    bf16x8 aq[2][2], bq[2][2];
#pragma unroll
    for (int m = 0; m < 2; ++m) {
      aq[m][0] = *(const bf16x8*)(Ab + aRow + m * 2048 + cs0);
      aq[m][1] = *(const bf16x8*)(Ab + aRow + m * 2048 + cs1);
      bq[m][0] = *(const bf16x8*)(Bb + bRow + m * 2048 + cs0);
      bq[m][1] = *(const bf16x8*)(Bb + bRow + m * 2048 + cs1);
    }
#pragma unroll
    for (int m = 0; m < 2; ++m)
#pragma unroll
      for (int n = 0; n < 2; ++n) {
        acc[m][n] = __builtin_amdgcn_mfma_f32_16x16x32_bf16(aq[m][0], bq[n][0], acc[m][n], 0, 0, 0);
        acc[m][n] = __builtin_amdgcn_mfma_f32_16x16x32_bf16(aq[m][1], bq[n][1], acc[m][n], 0, 0, 0);
      }
    asm volatile("" ::: "memory");
    __builtin_amdgcn_s_barrier();
  }

  // combine the two K-halves via LDS, write bf16
  __syncthreads();
  if (half == 1) {
#pragma unroll
    for (int m = 0; m < 2; ++m)
#pragma unroll
      for (int n = 0; n < 2; ++n)
        *(f32x4*)(smem + ((((hw << 2) + (m << 1) + n) << 6) + lane) * 16) = acc[m][n];
  }
  __syncthreads();
  if (half == 0) {
#pragma unroll
    for (int m = 0; m < 2; ++m)
#pragma unroll
      for (int n = 0; n < 2; ++n) {
        f32x4 p = *(const f32x4*)(smem + ((((hw << 2) + (m << 1) + n) << 6) + lane) * 16);
        int row = row0 + (wr << 5) + (m << 4) + (lk << 2);
        int col = col0 + (wc << 5) + (n << 4) + lr;
#pragma unroll
        for (int jj = 0; jj < 4; ++jj)
          t1out[(size_t)(row + jj) * 256 + col] = f2bf(acc[m][n][jj] + p[jj]);
      }
  }
}

// ---------------- main: 256x256 tile, 2-phase dbuf, counted vmcnt ------------
// 24 K-tiles (BK=64) over 6 panels (lowrank t1 + 5 butterfly). 8 waves of
// 128x64. Staging 64KB/tile into alternating 64KB LDS buffers; stage(t+1)
// always targets the opposite buffer from compute(t); vmcnt(8) = prev tile
// landed while next tile's 8 loads stay in flight. Grid 256 = 1 block/CU.
__global__ __launch_bounds__(512, 2) void main_gemm_kernel(
    const unsigned short* __restrict__ xb,
    const unsigned short* __restrict__ t1,
    const unsigned short* __restrict__ w2b,
    const unsigned short* __restrict__ weff,
    const int* __restrict__ flat,
    const float* __restrict__ bias,
    float* __restrict__ out) {
  __shared__ __align__(16) char smem[131072];  // 2 bufs x (A 32K | B 32K)
  const int tid  = threadIdx.x;
  const int lane = tid & 63;
  const int w    = tid >> 6;                   // 0..7
  const int wr   = w >> 2, wc = w & 3;         // wave = 128 rows x 64 cols
  const int lr   = lane & 15, lk = lane >> 4, lr7 = lr & 7;

  int bid = blockIdx.x;
  int swz = ((bid & 7) << 5) | (bid >> 3);     // bijective: 256 % 8 == 0
  const int bx = swz >> 4, by = swz & 15;
  const int row0 = bx << 8, col0 = by << 8;    // ob == by

  const int rr0 = tid >> 3;                    // 0..63
  const int csw = (tid & 7) ^ (rr0 & 7);

  const int base5 = by * 5;
  const int cA1 = (flat[base5 + 0] / 5) << 8;
  const int cA2 = (flat[base5 + 1] / 5) << 8;
  const int cA3 = (flat[base5 + 2] / 5) << 8;
  const int cA4 = (flat[base5 + 3] / 5) << 8;
  const int cA5 = (flat[base5 + 4] / 5) << 8;

  f32x4 acc[8][4];
#pragma unroll
  for (int m = 0; m < 8; ++m)
#pragma unroll
    for (int n = 0; n < 4; ++n) acc[m][n] = (f32x4){0.f, 0.f, 0.f, 0.f};

  // stage full K-tile T (A 32KB + B 32KB) into buf (T&1): 8 loads/thread
  auto stage = [&](int T) {
    int s = T >> 2, k0 = (T & 3) << 6;
    char* dstA = smem + ((T & 1) << 16) + (tid << 4);
    char* dstB = dstA + 32768;
    const unsigned short* Ab;
    int Astr;
    if (s == 0) { Ab = t1 + (size_t)row0 * 256; Astr = 256; }
    else {
      int colA = (s == 1) ? cA1 : (s == 2) ? cA2 : (s == 3) ? cA3
               : (s == 4) ? cA4 : cA5;
      Ab = xb + (size_t)row0 * 4096 + colA; Astr = 4096;
    }
    const unsigned short* Bb = (s == 0)
        ? (w2b + (size_t)col0 * 256)
        : (weff + ((size_t)(base5 + s - 1) << 16));
#pragma unroll
    for (int g = 0; g < 4; ++g) {
      int r = (g << 6) + rr0;
      const unsigned short* srcA = Ab + (size_t)r * Astr + k0 + csw * 8;
      __builtin_amdgcn_global_load_lds((gbl_cvoid*)srcA,
          (lds_void*)(dstA + (g << 13)), 16, 0, 0);
    }
#pragma unroll
    for (int g = 0; g < 4; ++g) {
      int r = (g << 6) + rr0;
      const unsigned short* srcB = Bb + (size_t)r * 256 + k0 + csw * 8;
      __builtin_amdgcn_global_load_lds((gbl_cvoid*)srcB,
          (lds_void*)(dstB + (g << 13)), 16, 0, 0);
    }
  };

  stage(0);
#pragma unroll 1
  for (int t = 0; t < 24; ++t) {
    if (t < 23) {
      stage(t + 1);
      asm volatile("s_waitcnt vmcnt(8)" ::: "memory");   // tile t landed
    } else {
      asm volatile("s_waitcnt vmcnt(0)" ::: "memory");
    }
    __builtin_amdgcn_s_barrier();
    const char* Ab = smem + ((t & 1) << 16);
    const char* Bb = Ab + 32768;
    bf16x8 bq[4][2];
#pragma unroll
    for (int n = 0; n < 4; ++n) {
      int row = (wc << 6) + (n << 4) + lr;
      bq[n][0] = *(const bf16x8*)(Bb + row * 128 + ((lk ^ lr7) << 4));
      bq[n][1] = *(const bf16x8*)(Bb + row * 128 + (((4 | lk) ^ lr7) << 4));
    }
#pragma unroll
    for (int m = 0; m < 8; ++m) {
      int row = (wr << 7) + (m << 4) + lr;
      bf16x8 a0 = *(const bf16x8*)(Ab + row * 128 + ((lk ^ lr7) << 4));
      bf16x8 a1 = *(const bf16x8*)(Ab + row * 128 + (((4 | lk) ^ lr7) << 4));
#pragma unroll
      for (int n = 0; n < 4; ++n)
        acc[m][n] = __builtin_amdgcn_mfma_f32_16x16x32_bf16(a0, bq[n][0], acc[m][n], 0, 0, 0);
#pragma unroll
      for (int n = 0; n < 4; ++n)
        acc[m][n] = __builtin_amdgcn_mfma_f32_16x16x32_bf16(a1, bq[n][1], acc[m][n], 0, 0, 0);
    }
    asm volatile("" ::: "memory");
    __builtin_amdgcn_s_barrier();
  }

  // epilogue: + bias, f32 store
#pragma unroll
  for (int n = 0; n < 4; ++n) {
    int col = col0 + (wc << 6) + (n << 4) + lr;
    float bv = bias[col];
#pragma unroll
    for (int m = 0; m < 8; ++m) {
      int row = row0 + (wr << 7) + (m << 4) + (lk << 2);
#pragma unroll
      for (int jj = 0; jj < 4; ++jj)
        out[(size_t)(row + jj) * 4096 + col] = acc[m][n][jj] + bv;
    }
  }
}

extern "C" void kernel_launch(void* const* d_in, const int* in_sizes, int n_in,
                              void* d_out, int out_size, void* d_ws, size_t ws_size,
                              hipStream_t stream) {
  const float* x      = (const float*)d_in[0];
  const float* weight = (const float*)d_in[1];
  const float* w1     = (const float*)d_in[2];
  const float* w2     = (const float*)d_in[3];
  const float* b      = (const float*)d_in[4];
  const int*   flat   = (const int*)d_in[5];
  float* out = (float*)d_out;

  char* ws = (char*)d_ws;
  unsigned short* xb   = (unsigned short*)(ws);                  // 32 MiB
  unsigned short* w1b  = (unsigned short*)(ws + 33554432);       // 2 MiB
  unsigned short* w2b  = (unsigned short*)(ws + 35651584);       // 2 MiB
  unsigned short* weff = (unsigned short*)(ws + 37748736);       // 10 MiB
  unsigned short* t1   = (unsigned short*)(ws + 48234496);       // 2 MiB

  prep_kernel<<<2048, 256, 0, stream>>>(x, weight, w1, w2, flat, xb, w1b, w2b, weff);
  t1_gemm_kernel<<<dim3(64, 4), 512, 0, stream>>>(xb, w1b, t1);
  main_gemm_kernel<<<256, 512, 0, stream>>>(xb, t1, w2b, weff, flat, b, out);
}